// Round 8
// baseline (279.160 us; speedup 1.0000x reference)
//
#include <hip/hip_runtime.h>
#include <hip/hip_bf16.h>
#include <math.h>

// Problem constants
#define BATCH 2
#define SLEN  2048
#define DIN   1024
#define DMODEL 1024
#define NHEAD 16
#define HD    64
#define E3    3072   // 3*DMODEL, row width of qkv

typedef unsigned short us;
typedef _Float16 f16;
typedef __attribute__((ext_vector_type(2))) _Float16 f16x2;
typedef __attribute__((ext_vector_type(8))) _Float16 f16x8;
typedef __attribute__((ext_vector_type(8))) unsigned short us8;
typedef __attribute__((ext_vector_type(4))) unsigned short us4;
typedef __attribute__((ext_vector_type(4))) unsigned int u32x4;
typedef __attribute__((ext_vector_type(4))) float f32x4;
typedef __attribute__((ext_vector_type(16))) float f32x16;

// 0.125 (1/sqrt(HD)) * log2(e): folded into Q at qkv-GEMM epilogue so the
// attention softmax is a bare exp2 of the raw MFMA score.
#define QSCALE 0.18033688011112042f

__device__ __forceinline__ us f16bits(float x) {
    const f16 h = (f16)x;
    return __builtin_bit_cast(us, h);
}

#define LD8(p) (__builtin_bit_cast(f16x8, *(const us8*)(p)))

// async 16B global->LDS (lane i deposits at ldsbase + i*16)
#define GLL16(g, l)                                                                     \
    __builtin_amdgcn_global_load_lds((const __attribute__((address_space(1))) unsigned int*)(g), \
                                     (__attribute__((address_space(3))) unsigned int*)(l), 16, 0, 0)

// ---------------- fp32 -> fp16 for x, w_qkv, w_o in one launch ----------------
__global__ __launch_bounds__(256) void cvt3_f16(
    const float* __restrict__ x, us* __restrict__ ox, int nx,
    const float* __restrict__ wq, us* __restrict__ owq, int nq,
    const float* __restrict__ wo, us* __restrict__ owo)
{
    int i = (blockIdx.x * 256 + threadIdx.x) * 8;
    const float* s;
    us* o;
    if (i < nx)           { s = x;  o = ox; }
    else if (i < nx + nq) { s = wq; o = owq; i -= nx; }
    else                  { s = wo; o = owo; i -= nx + nq; }
    const float4 f0 = *(const float4*)&s[i];
    const float4 f1 = *(const float4*)&s[i + 4];
    const float v[8] = {f0.x, f0.y, f0.z, f0.w, f1.x, f1.y, f1.z, f1.w};
    us8 h;
#pragma unroll
    for (int j = 0; j < 8; ++j) h[j] = f16bits(v[j]);
    *(us8*)&o[i] = h;
}

// ---------------- single-fp16 MFMA GEMM ----------------
// C[M,N] = A[M,K] * B[N,K]^T + bias[N], all fp16 inputs, fp32 accumulate.
// 128x128 tile, BK=32, 256 thr = 4 waves (2x2), 4x4 16x16 tiles per wave.
// QKV_OUT: Q cols (col%192<64) scaled by QSCALE -> qkv fp16; K cols -> qkv fp16;
//          V cols (col%192>=128) -> Vt[(b*16+h)*64+d][s] TRANSPOSED, b64-packed along s.
template <bool QKV_OUT>
__global__ __launch_bounds__(256) void gemm_f16(
    const us* __restrict__ Am, const us* __restrict__ Bm,
    const float* __restrict__ bias, void* __restrict__ Cout,
    us* __restrict__ VtOut, int M, int N, int K)
{
    __shared__ __align__(16) us As[128 * 32];
    __shared__ __align__(16) us Bs[128 * 32];

    const int t    = threadIdx.x;
    const int lane = t & 63;
    const int w    = t >> 6;
    const int ml   = lane & 15;
    const int quad = lane >> 4;
    const int wm   = w >> 1;
    const int wn   = w & 1;

    const int m0 = blockIdx.y * 128;
    const int n0 = blockIdx.x * 128;

    const int srow = (lane >> 2);
    const int scol = (lane & 3) * 8;

    const us* pA = Am + (size_t)(m0 + w * 32 + srow) * K + scol;
    const us* pB = Bm + (size_t)(n0 + w * 32 + srow) * K + scol;
    const size_t rstep = (size_t)16 * K;

    us* lA0 = &As[(w * 32) * 32];
    us* lA1 = &As[(w * 32 + 16) * 32];
    us* lB0 = &Bs[(w * 32) * 32];
    us* lB1 = &Bs[(w * 32 + 16) * 32];

    f32x4 acc[4][4];
#pragma unroll
    for (int i = 0; i < 4; ++i)
#pragma unroll
        for (int j = 0; j < 4; ++j) {
            acc[i][j][0] = 0.f; acc[i][j][1] = 0.f; acc[i][j][2] = 0.f; acc[i][j][3] = 0.f;
        }

    for (int k0 = 0; k0 < K; k0 += 32) {
        __syncthreads();
        GLL16(pA + k0, lA0); GLL16(pA + k0 + rstep, lA1);
        GLL16(pB + k0, lB0); GLL16(pB + k0 + rstep, lB1);
        __syncthreads();

        f16x8 a[4];
#pragma unroll
        for (int i = 0; i < 4; ++i)
            a[i] = __builtin_bit_cast(f16x8, *(const us8*)&As[(wm * 64 + i * 16 + ml) * 32 + quad * 8]);
#pragma unroll
        for (int j = 0; j < 4; ++j) {
            const f16x8 b = __builtin_bit_cast(f16x8, *(const us8*)&Bs[(wn * 64 + j * 16 + ml) * 32 + quad * 8]);
#pragma unroll
            for (int i = 0; i < 4; ++i)
                acc[i][j] = __builtin_amdgcn_mfma_f32_16x16x32_f16(a[i], b, acc[i][j], 0, 0, 0);
        }
    }

    if (QKV_OUT) {
        us* qkv = (us*)Cout;
#pragma unroll
        for (int j = 0; j < 4; ++j) {
            const int colbase = n0 + wn * 64 + j * 16;           // 16-aligned; class uniform
            const int cls = (colbase % 192) >> 6;                // 0=Q 1=K 2=V
            const float bjv = bias[colbase + ml];
            if (cls == 2) {
                const int head = colbase / 192;
                const int d = (colbase % 192) - 128 + ml;        // 0..63
#pragma unroll
                for (int i = 0; i < 4; ++i) {
                    const int rg = m0 + wm * 64 + i * 16 + quad * 4;  // 4 consecutive rows
                    const int bb = rg >> 11;
                    const int ss = rg & 2047;
                    us4 pp;
#pragma unroll
                    for (int r = 0; r < 4; ++r) pp[r] = f16bits(acc[i][j][r] + bjv);
                    *(us4*)&VtOut[((size_t)((bb * 16 + head) * 64 + d)) * SLEN + ss] = pp;
                }
            } else {
                const float sc = (cls == 0) ? QSCALE : 1.0f;
#pragma unroll
                for (int i = 0; i < 4; ++i) {
#pragma unroll
                    for (int r = 0; r < 4; ++r) {
                        const size_t rowoff = (size_t)(m0 + wm * 64 + i * 16 + quad * 4 + r) * N;
                        qkv[rowoff + colbase + ml] = f16bits((acc[i][j][r] + bjv) * sc);
                    }
                }
            }
        }
    } else {
        float* Cf = (float*)Cout;
        float bj[4];
#pragma unroll
        for (int j = 0; j < 4; ++j) bj[j] = bias[n0 + wn * 64 + j * 16 + ml];
#pragma unroll
        for (int i = 0; i < 4; ++i) {
#pragma unroll
            for (int r = 0; r < 4; ++r) {
                const size_t rowoff = (size_t)(m0 + wm * 64 + i * 16 + quad * 4 + r) * N;
#pragma unroll
                for (int j = 0; j < 4; ++j)
                    Cf[rowoff + n0 + wn * 64 + j * 16 + ml] = acc[i][j][r] + bj[j];
            }
        }
    }
}

// ---------------- barrier-free, LDS-free MFMA flash attention ----------------
// 4 independent waves/block, 32 q each. All fragments loaded straight from
// global (K rows from qkv; V rows from the pre-transposed vt buffer; L2-resident).
// S^T = K.Q^T (32x32x16). P C-layout -> B-frag layout purely in-register:
// C gives lane(m32,h) keys {8g+4h+r2}+32kt; B-frag s needs keys {16s+8h'+j}.
// j0..3 always live in the h=0 lane, j4..7 in the h=1 lane (same m32), group
// g = 2(s&1)+h_dest -> one shfl_xor(32) exchange of the partner-destined groups.
// l = per-lane f32 partial + one final shfl_xor(32). No __shared__, no barriers.
#define ACH 64
#define NCH (SLEN / ACH)

__global__ __launch_bounds__(256) void attn_mfma(
    const us* __restrict__ qkvh, const us* __restrict__ vtg, us* __restrict__ vals)
{
    const int t    = threadIdx.x;
    const int lane = t & 63;
    const int w    = t >> 6;
    const int m32  = lane & 31;
    const int h    = lane >> 5;

    const int bh = blockIdx.y;
    const int b  = bh >> 4;
    const int hd = bh & 15;
    const int q0 = blockIdx.x * 128 + w * 32;   // this wave's 32 queries

    const size_t base = (size_t)b * SLEN * E3;
    const int qoff = hd * 192;

    // ---- Q B-frags from global: lane n=q=m32, k = 16s + 8h + j ----
    f16x8 aq[4];
    {
        const us* qrow = qkvh + base + (size_t)(q0 + m32) * E3 + qoff + 8 * h;
#pragma unroll
        for (int s = 0; s < 4; ++s) aq[s] = LD8(qrow + 16 * s);
    }

    // ---- K / V^T row pointers ----
    const us* kp0 = qkvh + base + (size_t)m32 * E3 + qoff + 64 + 8 * h;   // kt=0 row
    const us* kp1 = kp0 + (size_t)32 * E3;                                // kt=1 row
    const us* vp0 = vtg + ((size_t)((b * 16 + hd) * 64 + m32)) * SLEN + 8 * h;  // dt=0
    const us* vp1 = vp0 + (size_t)32 * SLEN;                              // dt=1
    const size_t kstep = (size_t)ACH * E3;

    // ---- chunk 0 fragments ----
    f16x8 kk[8], vv[8];   // [kt*4+s], [dt*4+s]
#pragma unroll
    for (int s = 0; s < 4; ++s) {
        kk[s]     = LD8(kp0 + 16 * s);
        kk[4 + s] = LD8(kp1 + 16 * s);
        vv[s]     = LD8(vp0 + 16 * s);
        vv[4 + s] = LD8(vp1 + 16 * s);
    }

    f32x16 O[2];
#pragma unroll
    for (int dt = 0; dt < 2; ++dt)
#pragma unroll
        for (int r = 0; r < 16; ++r) O[dt][r] = 0.f;
    float lpart = 0.f;

    for (int c = 0; c < NCH; ++c) {
        // ---- S^T = K.Q^T (two independent 32x32 key tiles) ----
        f32x16 z[2];
#pragma unroll
        for (int kt = 0; kt < 2; ++kt)
#pragma unroll
            for (int r = 0; r < 16; ++r) z[kt][r] = 0.f;
#pragma unroll
        for (int s = 0; s < 4; ++s) {
            z[0] = __builtin_amdgcn_mfma_f32_32x32x16_f16(kk[s],     aq[s], z[0], 0, 0, 0);
            z[1] = __builtin_amdgcn_mfma_f32_32x32x16_f16(kk[4 + s], aq[s], z[1], 0, 0, 0);
        }
        // kk dead -> prefetch next chunk's K (hidden behind exp/PV)
        if (c + 1 < NCH) {
            const us* k0 = kp0 + (size_t)(c + 1) * kstep;
            const us* k1 = kp1 + (size_t)(c + 1) * kstep;
#pragma unroll
            for (int s = 0; s < 4; ++s) {
                kk[s]     = LD8(k0 + 16 * s);
                kk[4 + s] = LD8(k1 + 16 * s);
            }
        }

        // ---- exp2 + pack to fp16 pairs ----
        unsigned int pkw[2][4][2];   // [kt][g][r2-pair]
        float lp = 0.f;
#pragma unroll
        for (int kt = 0; kt < 2; ++kt) {
#pragma unroll
            for (int g = 0; g < 4; ++g) {
                const float p0 = __builtin_amdgcn_exp2f(z[kt][g * 4 + 0]);
                const float p1 = __builtin_amdgcn_exp2f(z[kt][g * 4 + 1]);
                const float p2 = __builtin_amdgcn_exp2f(z[kt][g * 4 + 2]);
                const float p3 = __builtin_amdgcn_exp2f(z[kt][g * 4 + 3]);
                lp += (p0 + p1) + (p2 + p3);
                pkw[kt][g][0] = __builtin_bit_cast(unsigned int, __builtin_amdgcn_cvt_pkrtz(p0, p1));
                pkw[kt][g][1] = __builtin_bit_cast(unsigned int, __builtin_amdgcn_cvt_pkrtz(p2, p3));
            }
        }
        lpart += lp;

        // ---- exchange partner-destined groups: lane h sends groups {2sl+1-h} ----
        unsigned int rw[2][2][2];
#pragma unroll
        for (int kt = 0; kt < 2; ++kt)
#pragma unroll
            for (int sl = 0; sl < 2; ++sl)
#pragma unroll
                for (int hw = 0; hw < 2; ++hw) {
                    const unsigned int send = h ? pkw[kt][2 * sl][hw] : pkw[kt][2 * sl + 1][hw];
                    rw[kt][sl][hw] = (unsigned int)__shfl_xor((int)send, 32);
                }

        // ---- assemble P B-frags: frag_s = h ? [recv | self g=2sl+1] : [self g=2sl | recv] ----
        f16x8 pf[4];
#pragma unroll
        for (int s = 0; s < 4; ++s) {
            const int kt = s >> 1, sl = s & 1;
            u32x4 wd;
            wd[0] = h ? rw[kt][sl][0] : pkw[kt][2 * sl][0];
            wd[1] = h ? rw[kt][sl][1] : pkw[kt][2 * sl][1];
            wd[2] = h ? pkw[kt][2 * sl + 1][0] : rw[kt][sl][0];
            wd[3] = h ? pkw[kt][2 * sl + 1][1] : rw[kt][sl][1];
            pf[s] = __builtin_bit_cast(f16x8, wd);
        }

        // ---- O^T += V^T.P^T ----
#pragma unroll
        for (int s = 0; s < 4; ++s) {
            O[0] = __builtin_amdgcn_mfma_f32_32x32x16_f16(vv[s],     pf[s], O[0], 0, 0, 0);
            O[1] = __builtin_amdgcn_mfma_f32_32x32x16_f16(vv[4 + s], pf[s], O[1], 0, 0, 0);
        }
        // vv dead -> prefetch next chunk's V
        if (c + 1 < NCH) {
            const us* v0 = vp0 + (c + 1) * ACH;
            const us* v1 = vp1 + (c + 1) * ACH;
#pragma unroll
            for (int s = 0; s < 4; ++s) {
                vv[s]     = LD8(v0 + 16 * s);
                vv[4 + s] = LD8(v1 + 16 * s);
            }
        }
    }

    // ---- epilogue: l = own + partner half; normalize; b64 fp16 stores ----
    const float l  = lpart + __shfl_xor(lpart, 32);
    const float rl = 1.0f / l;
    const int sq = q0 + m32;
    const size_t rowbase = (size_t)(b * SLEN + sq) * DMODEL + hd * HD;
#pragma unroll
    for (int dt = 0; dt < 2; ++dt) {
#pragma unroll
        for (int g = 0; g < 4; ++g) {
            us4 o4;
#pragma unroll
            for (int r2 = 0; r2 < 4; ++r2) o4[r2] = f16bits(O[dt][g * 4 + r2] * rl);
            *(us4*)&vals[rowbase + dt * 32 + 8 * g + 4 * h] = o4;
        }
    }
}

// ---------------- launch ----------------
extern "C" void kernel_launch(void* const* d_in, const int* in_sizes, int n_in,
                              void* d_out, int out_size, void* d_ws, size_t ws_size,
                              hipStream_t stream) {
    const float* x     = (const float*)d_in[0];
    const float* w_qkv = (const float*)d_in[1];
    const float* b_qkv = (const float*)d_in[2];
    const float* w_o   = (const float*)d_in[3];
    const float* b_o   = (const float*)d_in[4];
    float* out = (float*)d_out;

    const int M   = BATCH * SLEN;        // 4096
    const int XN  = M * DIN;             // 4,194,304
    const int WQN = E3 * DIN;            // 3,145,728
    const int WON = DMODEL * DMODEL;     // 1,048,576
    const size_t QKVN = (size_t)BATCH * SLEN * E3;            // 12,582,912
    const size_t VTN  = (size_t)BATCH * NHEAD * HD * SLEN;    //  4,194,304

    us* qkvh = (us*)d_ws;                // fp16 qkv (Q,K cols only) [QKVN]
    us* vtg  = qkvh + QKVN;              // fp16 V transposed [VTN]
    us* xh   = vtg + VTN;                // fp16 x [XN], reused for vals
    us* wq   = xh + XN;                  // fp16 w_qkv [WQN]
    us* wo   = wq + WQN;                 // fp16 w_o [WON]

    // 1) fp32 -> fp16 conversions, one launch
    cvt3_f16<<<dim3((XN + WQN + WON) / 2048), 256, 0, stream>>>(
        x, xh, XN, w_qkv, wq, WQN, w_o, wo);

    // 2) qkv projection: Q (scaled) + K -> qkvh; V -> vtg transposed
    gemm_f16<true><<<dim3(E3 / 128, M / 128), 256, 0, stream>>>(
        xh, wq, b_qkv, qkvh, vtg, M, E3, DIN);

    // 3) attention -> vals fp16 (reuse x plane; x is dead)
    us* vals = xh;
    attn_mfma<<<dim3(SLEN / 128, BATCH * NHEAD), 256, 0, stream>>>(qkvh, vtg, vals);

    // 4) out = vals @ w_o^T + b_o -> fp32
    gemm_f16<false><<<dim3(DMODEL / 128, M / 128), 256, 0, stream>>>(
        vals, wo, b_o, out, nullptr, M, DMODEL, DMODEL);
}

// Round 9
// 206.704 us; speedup vs baseline: 1.3505x; 1.3505x over previous
//
#include <hip/hip_runtime.h>
#include <hip/hip_bf16.h>
#include <math.h>

// Problem constants
#define BATCH 2
#define SLEN  2048
#define DIN   1024
#define DMODEL 1024
#define NHEAD 16
#define HD    64
#define E3    3072   // 3*DMODEL, row width of qkv

typedef unsigned short us;
typedef _Float16 f16;
typedef __attribute__((ext_vector_type(8))) _Float16 f16x8;
typedef __attribute__((ext_vector_type(8))) unsigned short us8;
typedef __attribute__((ext_vector_type(4))) unsigned short us4;
typedef __attribute__((ext_vector_type(4))) unsigned int u32x4;
typedef __attribute__((ext_vector_type(4))) float f32x4;
typedef __attribute__((ext_vector_type(16))) float f32x16;

// 0.125 (1/sqrt(HD)) * log2(e): folded into Q at qkv-GEMM epilogue so the
// attention softmax is a bare exp2 of the raw MFMA score.
#define QSCALE 0.18033688011112042f

__device__ __forceinline__ us f16bits(float x) {
    const f16 h = (f16)x;
    return __builtin_bit_cast(us, h);
}

#define LD8(p) (__builtin_bit_cast(f16x8, *(const us8*)(p)))

// async 16B global->LDS (lane i deposits at ldsbase + i*16)
#define GLL16(g, l)                                                                     \
    __builtin_amdgcn_global_load_lds((const __attribute__((address_space(1))) unsigned int*)(g), \
                                     (__attribute__((address_space(3))) unsigned int*)(l), 16, 0, 0)

// ---------------- fp32 -> fp16 for x, w_qkv, w_o in one launch ----------------
__global__ __launch_bounds__(256) void cvt3_f16(
    const float* __restrict__ x, us* __restrict__ ox, int nx,
    const float* __restrict__ wq, us* __restrict__ owq, int nq,
    const float* __restrict__ wo, us* __restrict__ owo)
{
    int i = (blockIdx.x * 256 + threadIdx.x) * 8;
    const float* s;
    us* o;
    if (i < nx)           { s = x;  o = ox; }
    else if (i < nx + nq) { s = wq; o = owq; i -= nx; }
    else                  { s = wo; o = owo; i -= nx + nq; }
    const float4 f0 = *(const float4*)&s[i];
    const float4 f1 = *(const float4*)&s[i + 4];
    const float v[8] = {f0.x, f0.y, f0.z, f0.w, f1.x, f1.y, f1.z, f1.w};
    us8 h;
#pragma unroll
    for (int j = 0; j < 8; ++j) h[j] = f16bits(v[j]);
    *(us8*)&o[i] = h;
}

// ---------------- single-fp16 MFMA GEMM ----------------
// C[M,N] = A[M,K] * B[N,K]^T + bias[N], all fp16 inputs, fp32 accumulate.
// 128x128 tile, BK=32, 256 thr = 4 waves (2x2), 4x4 16x16 tiles per wave.
// QKV_OUT: Q cols (col%192<64) scaled by QSCALE -> qkv fp16; K cols -> qkv fp16;
//          V cols (col%192>=128) -> Vt[(b*16+h)*64+d][s] TRANSPOSED, b64-packed along s.
template <bool QKV_OUT>
__global__ __launch_bounds__(256) void gemm_f16(
    const us* __restrict__ Am, const us* __restrict__ Bm,
    const float* __restrict__ bias, void* __restrict__ Cout,
    us* __restrict__ VtOut, int M, int N, int K)
{
    __shared__ __align__(16) us As[128 * 32];
    __shared__ __align__(16) us Bs[128 * 32];

    const int t    = threadIdx.x;
    const int lane = t & 63;
    const int w    = t >> 6;
    const int ml   = lane & 15;
    const int quad = lane >> 4;
    const int wm   = w >> 1;
    const int wn   = w & 1;

    const int m0 = blockIdx.y * 128;
    const int n0 = blockIdx.x * 128;

    const int srow = (lane >> 2);
    const int scol = (lane & 3) * 8;

    const us* pA = Am + (size_t)(m0 + w * 32 + srow) * K + scol;
    const us* pB = Bm + (size_t)(n0 + w * 32 + srow) * K + scol;
    const size_t rstep = (size_t)16 * K;

    us* lA0 = &As[(w * 32) * 32];
    us* lA1 = &As[(w * 32 + 16) * 32];
    us* lB0 = &Bs[(w * 32) * 32];
    us* lB1 = &Bs[(w * 32 + 16) * 32];

    f32x4 acc[4][4];
#pragma unroll
    for (int i = 0; i < 4; ++i)
#pragma unroll
        for (int j = 0; j < 4; ++j) {
            acc[i][j][0] = 0.f; acc[i][j][1] = 0.f; acc[i][j][2] = 0.f; acc[i][j][3] = 0.f;
        }

    for (int k0 = 0; k0 < K; k0 += 32) {
        __syncthreads();
        GLL16(pA + k0, lA0); GLL16(pA + k0 + rstep, lA1);
        GLL16(pB + k0, lB0); GLL16(pB + k0 + rstep, lB1);
        __syncthreads();

        f16x8 a[4];
#pragma unroll
        for (int i = 0; i < 4; ++i)
            a[i] = __builtin_bit_cast(f16x8, *(const us8*)&As[(wm * 64 + i * 16 + ml) * 32 + quad * 8]);
#pragma unroll
        for (int j = 0; j < 4; ++j) {
            const f16x8 b = __builtin_bit_cast(f16x8, *(const us8*)&Bs[(wn * 64 + j * 16 + ml) * 32 + quad * 8]);
#pragma unroll
            for (int i = 0; i < 4; ++i)
                acc[i][j] = __builtin_amdgcn_mfma_f32_16x16x32_f16(a[i], b, acc[i][j], 0, 0, 0);
        }
    }

    if (QKV_OUT) {
        us* qkv = (us*)Cout;
#pragma unroll
        for (int j = 0; j < 4; ++j) {
            const int colbase = n0 + wn * 64 + j * 16;           // 16-aligned; class uniform
            const int cls = (colbase % 192) >> 6;                // 0=Q 1=K 2=V
            const float bjv = bias[colbase + ml];
            if (cls == 2) {
                const int head = colbase / 192;
                const int d = (colbase % 192) - 128 + ml;        // 0..63
#pragma unroll
                for (int i = 0; i < 4; ++i) {
                    const int rg = m0 + wm * 64 + i * 16 + quad * 4;  // 4 consecutive rows
                    const int bb = rg >> 11;
                    const int ss = rg & 2047;
                    us4 pp;
#pragma unroll
                    for (int r = 0; r < 4; ++r) pp[r] = f16bits(acc[i][j][r] + bjv);
                    *(us4*)&VtOut[((size_t)((bb * 16 + head) * 64 + d)) * SLEN + ss] = pp;
                }
            } else {
                const float sc = (cls == 0) ? QSCALE : 1.0f;
#pragma unroll
                for (int i = 0; i < 4; ++i) {
#pragma unroll
                    for (int r = 0; r < 4; ++r) {
                        const size_t rowoff = (size_t)(m0 + wm * 64 + i * 16 + quad * 4 + r) * N;
                        qkv[rowoff + colbase + ml] = f16bits((acc[i][j][r] + bjv) * sc);
                    }
                }
            }
        }
    } else {
        float* Cf = (float*)Cout;
        float bj[4];
#pragma unroll
        for (int j = 0; j < 4; ++j) bj[j] = bias[n0 + wn * 64 + j * 16 + ml];
#pragma unroll
        for (int i = 0; i < 4; ++i) {
#pragma unroll
            for (int r = 0; r < 4; ++r) {
                const size_t rowoff = (size_t)(m0 + wm * 64 + i * 16 + quad * 4 + r) * N;
#pragma unroll
                for (int j = 0; j < 4; ++j)
                    Cf[rowoff + n0 + wn * 64 + j * 16 + ml] = acc[i][j][r] + bj[j];
            }
        }
    }
}

// ---------------- MFMA flash attention: GLL16-staged, dbuf, in-register P ----------------
// Blocks of 128 thr = 2 waves x 32 q (ABQ=64); grid 32 x 32 = 1024 -> 4 blocks/CU.
// K and V(pre-transposed vtg) staged via global_load_lds w=16 into unpadded
// [row][64] tiles, XOR seg-swizzle (seg ^ (r&7) ^ (((r>>3)&1)<<2)) folded into
// the per-lane GLOBAL address -> frag ds_read_b128 is <=2-way (free).
// Double-buffered: stage(c+1) issued right after the barrier, drained at the
// NEXT barrier -> DMA overlaps the whole compute phase. One barrier per chunk.
// S^T = K.Q^T (32x32x16); P C-layout -> B-frag purely in-register via one
// shfl_xor(32) group exchange (HW-verified round 8); l per-lane + final shfl.
#define ABQ 64
#define ACH 64
#define NCH (SLEN / ACH)

__global__ __launch_bounds__(128) void attn_mfma(
    const us* __restrict__ qkvh, const us* __restrict__ vtg, us* __restrict__ vals)
{
    __shared__ __align__(16) us Ks[2][ACH * 64];   // 16 KB
    __shared__ __align__(16) us Vs[2][HD * 64];    // 16 KB

    const int t    = threadIdx.x;
    const int lane = t & 63;
    const int w    = t >> 6;        // wave 0..1
    const int m32  = lane & 31;
    const int h    = lane >> 5;

    const int bh = blockIdx.y;
    const int b  = bh >> 4;
    const int hd = bh & 15;
    const int q0 = blockIdx.x * ABQ + w * 32;   // this wave's 32 queries

    const size_t base = (size_t)b * SLEN * E3;
    const int qoff = hd * 192;

    // ---- Q B-frags straight from global (one-time): lane n=q=m32, k=16s+8h+j ----
    f16x8 aq[4];
    {
        const us* qrow = qkvh + base + (size_t)(q0 + m32) * E3 + qoff + 8 * h;
#pragma unroll
        for (int s = 0; s < 4; ++s) aq[s] = LD8(qrow + 16 * s);
    }

    // ---- staging addresses: wave w stages rows [w*32, w*32+32) of K and of V^T.
    // Instr g covers 8 rows; lane i: rloc=i>>3, phys_seg=i&7,
    // logical seg = (i&7) ^ rloc ^ ((g&1)<<2).
    const int rloc = lane >> 3;
    const us* kgp[4];
    const us* vgp[4];
#pragma unroll
    for (int g = 0; g < 4; ++g) {
        const int row  = w * 32 + g * 8 + rloc;
        const int segl = (lane & 7) ^ rloc ^ ((g & 1) << 2);
        kgp[g] = qkvh + base + (size_t)row * E3 + qoff + 64 + segl * 8;
        vgp[g] = vtg + ((size_t)(bh * 64 + row)) * SLEN + segl * 8;
    }
    const size_t kstep = (size_t)ACH * E3;

    // ---- stage chunk 0 into buf 0 ----
#pragma unroll
    for (int g = 0; g < 4; ++g) {
        GLL16(kgp[g], &Ks[0][(w * 32 + g * 8) * 64]);
        GLL16(vgp[g], &Vs[0][(w * 32 + g * 8) * 64]);
    }

    // frag-read swizzle for this lane (same for K and V; row = kt/dt*32 + m32)
    const int fsw = (m32 & 7) ^ (((m32 >> 3) & 1) << 2);

    f32x16 O[2];
#pragma unroll
    for (int dt = 0; dt < 2; ++dt)
#pragma unroll
        for (int r = 0; r < 16; ++r) O[dt][r] = 0.f;
    float lpart = 0.f;

    for (int c = 0; c < NCH; ++c) {
        const int buf = c & 1;
        __syncthreads();   // drains this wave's GLL16s for buf; all waves done with buf^1
        if (c + 1 < NCH) {
#pragma unroll
            for (int g = 0; g < 4; ++g) {
                GLL16(kgp[g] + (size_t)(c + 1) * kstep, &Ks[buf ^ 1][(w * 32 + g * 8) * 64]);
                GLL16(vgp[g] + (size_t)(c + 1) * ACH,   &Vs[buf ^ 1][(w * 32 + g * 8) * 64]);
            }
        }

        // ---- S^T = K.Q^T (two 32x32 key tiles) ----
        f32x16 z[2];
#pragma unroll
        for (int kt = 0; kt < 2; ++kt)
#pragma unroll
            for (int r = 0; r < 16; ++r) z[kt][r] = 0.f;
#pragma unroll
        for (int s = 0; s < 4; ++s) {
            const int ps = ((2 * s + h) ^ fsw) * 8;
            const f16x8 ak0 = LD8(&Ks[buf][(m32) * 64 + ps]);
            const f16x8 ak1 = LD8(&Ks[buf][(32 + m32) * 64 + ps]);
            z[0] = __builtin_amdgcn_mfma_f32_32x32x16_f16(ak0, aq[s], z[0], 0, 0, 0);
            z[1] = __builtin_amdgcn_mfma_f32_32x32x16_f16(ak1, aq[s], z[1], 0, 0, 0);
        }

        // ---- exp2 + pack to fp16 pairs ----
        unsigned int pkw[2][4][2];   // [kt][g][pair]
        float lp = 0.f;
#pragma unroll
        for (int kt = 0; kt < 2; ++kt) {
#pragma unroll
            for (int g = 0; g < 4; ++g) {
                const float p0 = __builtin_amdgcn_exp2f(z[kt][g * 4 + 0]);
                const float p1 = __builtin_amdgcn_exp2f(z[kt][g * 4 + 1]);
                const float p2 = __builtin_amdgcn_exp2f(z[kt][g * 4 + 2]);
                const float p3 = __builtin_amdgcn_exp2f(z[kt][g * 4 + 3]);
                lp += (p0 + p1) + (p2 + p3);
                pkw[kt][g][0] = __builtin_bit_cast(unsigned int, __builtin_amdgcn_cvt_pkrtz(p0, p1));
                pkw[kt][g][1] = __builtin_bit_cast(unsigned int, __builtin_amdgcn_cvt_pkrtz(p2, p3));
            }
        }
        lpart += lp;

        // ---- exchange partner-destined groups: lane h sends groups {2sl+1-h} ----
        unsigned int rw[2][2][2];
#pragma unroll
        for (int kt = 0; kt < 2; ++kt)
#pragma unroll
            for (int sl = 0; sl < 2; ++sl)
#pragma unroll
                for (int hw = 0; hw < 2; ++hw) {
                    const unsigned int send = h ? pkw[kt][2 * sl][hw] : pkw[kt][2 * sl + 1][hw];
                    rw[kt][sl][hw] = (unsigned int)__shfl_xor((int)send, 32);
                }

        // ---- assemble P B-frags ----
        f16x8 pf[4];
#pragma unroll
        for (int s = 0; s < 4; ++s) {
            const int kt = s >> 1, sl = s & 1;
            u32x4 wd;
            wd[0] = h ? rw[kt][sl][0] : pkw[kt][2 * sl][0];
            wd[1] = h ? rw[kt][sl][1] : pkw[kt][2 * sl][1];
            wd[2] = h ? pkw[kt][2 * sl + 1][0] : rw[kt][sl][0];
            wd[3] = h ? pkw[kt][2 * sl + 1][1] : rw[kt][sl][1];
            pf[s] = __builtin_bit_cast(f16x8, wd);
        }

        // ---- O^T += V^T.P^T ----
#pragma unroll
        for (int s = 0; s < 4; ++s) {
            const int ps = ((2 * s + h) ^ fsw) * 8;
            const f16x8 av0 = LD8(&Vs[buf][(m32) * 64 + ps]);
            const f16x8 av1 = LD8(&Vs[buf][(32 + m32) * 64 + ps]);
            O[0] = __builtin_amdgcn_mfma_f32_32x32x16_f16(av0, pf[s], O[0], 0, 0, 0);
            O[1] = __builtin_amdgcn_mfma_f32_32x32x16_f16(av1, pf[s], O[1], 0, 0, 0);
        }
    }

    // ---- epilogue: l = own + partner half; normalize; b64 fp16 stores ----
    const float l  = lpart + __shfl_xor(lpart, 32);
    const float rl = 1.0f / l;
    const int sq = q0 + m32;
    const size_t rowbase = (size_t)(b * SLEN + sq) * DMODEL + hd * HD;
#pragma unroll
    for (int dt = 0; dt < 2; ++dt) {
#pragma unroll
        for (int g = 0; g < 4; ++g) {
            us4 o4;
#pragma unroll
            for (int r2 = 0; r2 < 4; ++r2) o4[r2] = f16bits(O[dt][g * 4 + r2] * rl);
            *(us4*)&vals[rowbase + dt * 32 + 8 * g + 4 * h] = o4;
        }
    }
}

// ---------------- launch ----------------
extern "C" void kernel_launch(void* const* d_in, const int* in_sizes, int n_in,
                              void* d_out, int out_size, void* d_ws, size_t ws_size,
                              hipStream_t stream) {
    const float* x     = (const float*)d_in[0];
    const float* w_qkv = (const float*)d_in[1];
    const float* b_qkv = (const float*)d_in[2];
    const float* w_o   = (const float*)d_in[3];
    const float* b_o   = (const float*)d_in[4];
    float* out = (float*)d_out;

    const int M   = BATCH * SLEN;        // 4096
    const int XN  = M * DIN;             // 4,194,304
    const int WQN = E3 * DIN;            // 3,145,728
    const int WON = DMODEL * DMODEL;     // 1,048,576
    const size_t QKVN = (size_t)BATCH * SLEN * E3;            // 12,582,912
    const size_t VTN  = (size_t)BATCH * NHEAD * HD * SLEN;    //  4,194,304

    us* qkvh = (us*)d_ws;                // fp16 qkv (Q,K cols) [QKVN]
    us* vtg  = qkvh + QKVN;              // fp16 V transposed [VTN]
    us* xh   = vtg + VTN;                // fp16 x [XN], reused for vals
    us* wq   = xh + XN;                  // fp16 w_qkv [WQN]
    us* wo   = wq + WQN;                 // fp16 w_o [WON]

    // 1) fp32 -> fp16 conversions, one launch
    cvt3_f16<<<dim3((XN + WQN + WON) / 2048), 256, 0, stream>>>(
        x, xh, XN, w_qkv, wq, WQN, w_o, wo);

    // 2) qkv projection: Q (scaled) + K -> qkvh; V -> vtg transposed
    gemm_f16<true><<<dim3(E3 / 128, M / 128), 256, 0, stream>>>(
        xh, wq, b_qkv, qkvh, vtg, M, E3, DIN);

    // 3) attention -> vals fp16 (reuse x plane; x is dead)
    us* vals = xh;
    attn_mfma<<<dim3(SLEN / ABQ, BATCH * NHEAD), 128, 0, stream>>>(qkvh, vtg, vals);

    // 4) out = vals @ w_o^T + b_o -> fp32
    gemm_f16<false><<<dim3(DMODEL / 128, M / 128), 256, 0, stream>>>(
        vals, wo, b_o, out, nullptr, M, DMODEL, DMODEL);
}

// Round 10
// 206.185 us; speedup vs baseline: 1.3539x; 1.0025x over previous
//
#include <hip/hip_runtime.h>
#include <hip/hip_bf16.h>
#include <math.h>

// Problem constants
#define BATCH 2
#define SLEN  2048
#define DIN   1024
#define DMODEL 1024
#define NHEAD 16
#define HD    64
#define E3    3072   // 3*DMODEL

typedef unsigned short us;
typedef _Float16 f16;
typedef __attribute__((ext_vector_type(8))) _Float16 f16x8;
typedef __attribute__((ext_vector_type(8))) unsigned short us8;
typedef __attribute__((ext_vector_type(4))) unsigned short us4;
typedef __attribute__((ext_vector_type(4))) unsigned int u32x4;
typedef __attribute__((ext_vector_type(4))) float f32x4;
typedef __attribute__((ext_vector_type(16))) float f32x16;

// 0.125 (1/sqrt(HD)) * log2(e), folded into Q at the qkv-GEMM epilogue.
#define QSCALE 0.18033688011112042f

__device__ __forceinline__ us f16bits(float x) {
    const f16 h = (f16)x;
    return __builtin_bit_cast(us, h);
}

#define LD8(p) (__builtin_bit_cast(f16x8, *(const us8*)(p)))

// async 16B global->LDS (lane i deposits at ldsbase + i*16)
#define GLL16(g, l)                                                                     \
    __builtin_amdgcn_global_load_lds((const __attribute__((address_space(1))) unsigned int*)(g), \
                                     (__attribute__((address_space(3))) unsigned int*)(l), 16, 0, 0)

// ---------------- fp32 -> fp16 for x, w_qkv, w_o in one launch ----------------
__global__ __launch_bounds__(256) void cvt3_f16(
    const float* __restrict__ x, us* __restrict__ ox, int nx,
    const float* __restrict__ wq, us* __restrict__ owq, int nq,
    const float* __restrict__ wo, us* __restrict__ owo)
{
    int i = (blockIdx.x * 256 + threadIdx.x) * 8;
    const float* s;
    us* o;
    if (i < nx)           { s = x;  o = ox; }
    else if (i < nx + nq) { s = wq; o = owq; i -= nx; }
    else                  { s = wo; o = owo; i -= nx + nq; }
    const float4 f0 = *(const float4*)&s[i];
    const float4 f1 = *(const float4*)&s[i + 4];
    const float v[8] = {f0.x, f0.y, f0.z, f0.w, f1.x, f1.y, f1.z, f1.w};
    us8 h;
#pragma unroll
    for (int j = 0; j < 8; ++j) h[j] = f16bits(v[j]);
    *(us8*)&o[i] = h;
}

// ---------------- single-fp16 MFMA GEMM ----------------
// C[M,N] = A[M,K]*B[N,K]^T + bias. 128x128 tile, BK=32, 4 waves.
// QKV_OUT: write Q/K/V into MFMA-frag-native buffers:
//   per (bh, tile, s): 512-f16 block; element (h*32+m32)*8+j is lane (h*32+m32)'s
//   j-th f16 of its frag — attention reads LD8(block + lane*8), fully coalesced.
//   Q (B-op):  qfn[bh][qt(64)][s(4)]  elem (hd8*32+q32)*8+jd  <- Q[qt*32+q32][16s+8hd8+jd] * QSCALE
//   K (A-op):  kfn[bh][c(32)][kt(2)][s(4)] elem (hd8*32+k32)*8+jd <- K[c*64+kt*32+k32][16s+8hd8+jd]
//   V^T(A-op): vfn[bh][c(32)][dt(2)][s(4)] elem (hk8*32+d32)*8+jk <- V[c*64+16s+8hk8+jk][dt*32+d32]
template <bool QKV_OUT>
__global__ __launch_bounds__(256) void gemm_f16(
    const us* __restrict__ Am, const us* __restrict__ Bm,
    const float* __restrict__ bias, void* __restrict__ Cout,
    us* __restrict__ Qfn, us* __restrict__ Kfn, us* __restrict__ Vfn,
    int M, int N, int K)
{
    __shared__ __align__(16) us As[128 * 32];
    __shared__ __align__(16) us Bs[128 * 32];

    const int t    = threadIdx.x;
    const int lane = t & 63;
    const int w    = t >> 6;
    const int ml   = lane & 15;
    const int quad = lane >> 4;
    const int wm   = w >> 1;
    const int wn   = w & 1;

    const int m0 = blockIdx.y * 128;
    const int n0 = blockIdx.x * 128;

    const int srow = (lane >> 2);
    const int scol = (lane & 3) * 8;

    const us* pA = Am + (size_t)(m0 + w * 32 + srow) * K + scol;
    const us* pB = Bm + (size_t)(n0 + w * 32 + srow) * K + scol;
    const size_t rstep = (size_t)16 * K;

    us* lA0 = &As[(w * 32) * 32];
    us* lA1 = &As[(w * 32 + 16) * 32];
    us* lB0 = &Bs[(w * 32) * 32];
    us* lB1 = &Bs[(w * 32 + 16) * 32];

    f32x4 acc[4][4];
#pragma unroll
    for (int i = 0; i < 4; ++i)
#pragma unroll
        for (int j = 0; j < 4; ++j) {
            acc[i][j][0] = 0.f; acc[i][j][1] = 0.f; acc[i][j][2] = 0.f; acc[i][j][3] = 0.f;
        }

    for (int k0 = 0; k0 < K; k0 += 32) {
        __syncthreads();
        GLL16(pA + k0, lA0); GLL16(pA + k0 + rstep, lA1);
        GLL16(pB + k0, lB0); GLL16(pB + k0 + rstep, lB1);
        __syncthreads();

        f16x8 a[4];
#pragma unroll
        for (int i = 0; i < 4; ++i)
            a[i] = __builtin_bit_cast(f16x8, *(const us8*)&As[(wm * 64 + i * 16 + ml) * 32 + quad * 8]);
#pragma unroll
        for (int j = 0; j < 4; ++j) {
            const f16x8 b = __builtin_bit_cast(f16x8, *(const us8*)&Bs[(wn * 64 + j * 16 + ml) * 32 + quad * 8]);
#pragma unroll
            for (int i = 0; i < 4; ++i)
                acc[i][j] = __builtin_amdgcn_mfma_f32_16x16x32_f16(a[i], b, acc[i][j], 0, 0, 0);
        }
    }

    if (QKV_OUT) {
#pragma unroll
        for (int j = 0; j < 4; ++j) {
            const int colbase = n0 + wn * 64 + j * 16;   // multiple of 16
            const int head = colbase / 192;
            const int cm   = colbase % 192;              // {0,16,...,176}
            const int cls  = cm >> 6;                    // 0=Q 1=K 2=V
            const float bjv = bias[colbase + ml];
            if (cls == 0) {
                const int s = cm >> 4;                   // dim-segment 0..3
                const int hml = ml >> 3, jml = ml & 7;
#pragma unroll
                for (int i = 0; i < 4; ++i) {
                    const int rg = m0 + wm * 64 + i * 16 + quad * 4;
                    const int bb = rg >> 11, sr = rg & 2047;
                    const size_t blk = ((((size_t)(bb * 16 + head) * 64 + (sr >> 5)) * 4 + s) << 9)
                                       + hml * 256 + jml;
                    const int q32 = sr & 31;
#pragma unroll
                    for (int r = 0; r < 4; ++r)
                        Qfn[blk + (size_t)(q32 + r) * 8] = f16bits((acc[i][j][r] + bjv) * QSCALE);
                }
            } else if (cls == 1) {
                const int s = (cm - 64) >> 4;
                const int hml = ml >> 3, jml = ml & 7;
#pragma unroll
                for (int i = 0; i < 4; ++i) {
                    const int rg = m0 + wm * 64 + i * 16 + quad * 4;
                    const int bb = rg >> 11, sr = rg & 2047;
                    const size_t blk = (((((size_t)(bb * 16 + head) * 32 + (sr >> 6)) * 2
                                        + ((sr >> 5) & 1)) * 4 + s) << 9) + hml * 256 + jml;
                    const int k32 = sr & 31;
#pragma unroll
                    for (int r = 0; r < 4; ++r)
                        Kfn[blk + (size_t)(k32 + r) * 8] = f16bits(acc[i][j][r] + bjv);
                }
            } else {
                const int d0 = cm - 128;                 // {0,16,32,48}
                const int dt = d0 >> 5;
                const int m32v = (d0 & 31) + ml;
#pragma unroll
                for (int i = 0; i < 4; ++i) {
                    const int rg = m0 + wm * 64 + i * 16 + quad * 4;   // key of r=0
                    const int bb = rg >> 11, sr = rg & 2047;
                    const int s  = (sr >> 4) & 3;
                    const int hk = (sr >> 3) & 1;
                    const int j0 = sr & 7;               // (quad&1)*4; r adds 0..3
                    const size_t blk = (((((size_t)(bb * 16 + head) * 32 + (sr >> 6)) * 2
                                        + dt) * 4 + s) << 9) + hk * 256 + (size_t)m32v * 8 + j0;
                    us4 pp;
#pragma unroll
                    for (int r = 0; r < 4; ++r) pp[r] = f16bits(acc[i][j][r] + bjv);
                    *(us4*)&Vfn[blk] = pp;
                }
            }
        }
    } else {
        float* Cf = (float*)Cout;
        float bj[4];
#pragma unroll
        for (int j = 0; j < 4; ++j) bj[j] = bias[n0 + wn * 64 + j * 16 + ml];
#pragma unroll
        for (int i = 0; i < 4; ++i) {
#pragma unroll
            for (int r = 0; r < 4; ++r) {
                const size_t rowoff = (size_t)(m0 + wm * 64 + i * 16 + quad * 4 + r) * N;
#pragma unroll
                for (int j = 0; j < 4; ++j)
                    Cf[rowoff + n0 + wn * 64 + j * 16 + ml] = acc[i][j][r] + bj[j];
            }
        }
    }
}

// ---------------- LDS-free, barrier-free MFMA flash attention ----------------
// 4 independent waves/block, 32 q each (frag-native coalesced loads: every frag
// is LD8(block + lane*8) = one 1 KB contiguous wave-load from L2).
// S^T = K.Q^T (32x32x16); P C-layout -> B-frag in-register via one shfl_xor(32)
// group exchange (HW-verified r8/r9); l per-lane + final shfl. K/V frags for
// chunk c+1 reloaded into the same registers right after last use.
#define NCH (SLEN / 64)

__global__ __launch_bounds__(256) void attn_mfma(
    const us* __restrict__ qfn, const us* __restrict__ kfn,
    const us* __restrict__ vfn, us* __restrict__ vals)
{
    const int t    = threadIdx.x;
    const int lane = t & 63;
    const int w    = t >> 6;
    const int m32  = lane & 31;
    const int h    = lane >> 5;

    const int bh = blockIdx.y;
    const int b  = bh >> 4;
    const int hd = bh & 15;
    const int qt = blockIdx.x * 4 + w;     // q-tile 0..63 (32 queries)

    // ---- Q B-frags (one-time, coalesced) ----
    f16x8 aq[4];
    {
        const us* qp = qfn + (((size_t)bh * 64 + qt) * 4 << 9) + lane * 8;
#pragma unroll
        for (int s = 0; s < 4; ++s) aq[s] = LD8(qp + (s << 9));
    }

    // ---- chunk base pointers (chunk stride = 2*4*512 = 4096 f16) ----
    const us* kp = kfn + (((size_t)bh * 32) << 12) + lane * 8;
    const us* vp = vfn + (((size_t)bh * 32) << 12) + lane * 8;

    // ---- chunk 0 fragments: kk[kt*4+s], vv[dt*4+s] ----
    f16x8 kk[8], vv[8];
#pragma unroll
    for (int u = 0; u < 8; ++u) {
        kk[u] = LD8(kp + (((u >> 2) * 4 + (u & 3)) << 9));
        vv[u] = LD8(vp + (((u >> 2) * 4 + (u & 3)) << 9));
    }

    f32x16 O[2];
#pragma unroll
    for (int dt = 0; dt < 2; ++dt)
#pragma unroll
        for (int r = 0; r < 16; ++r) O[dt][r] = 0.f;
    float lpart = 0.f;

    for (int c = 0; c < NCH; ++c) {
        // ---- S^T = K.Q^T (two 32x32 key tiles) ----
        f32x16 z[2];
#pragma unroll
        for (int kt = 0; kt < 2; ++kt)
#pragma unroll
            for (int r = 0; r < 16; ++r) z[kt][r] = 0.f;
#pragma unroll
        for (int s = 0; s < 4; ++s) {
            z[0] = __builtin_amdgcn_mfma_f32_32x32x16_f16(kk[s],     aq[s], z[0], 0, 0, 0);
            z[1] = __builtin_amdgcn_mfma_f32_32x32x16_f16(kk[4 + s], aq[s], z[1], 0, 0, 0);
        }
        // kk dead -> prefetch next chunk's K (hidden behind exp/PV)
        if (c + 1 < NCH) {
            const us* kn = kp + ((size_t)(c + 1) << 12);
#pragma unroll
            for (int u = 0; u < 8; ++u)
                kk[u] = LD8(kn + (((u >> 2) * 4 + (u & 3)) << 9));
        }

        // ---- exp2 + pack to fp16 pairs ----
        unsigned int pkw[2][4][2];   // [kt][g][pair]
        float lp = 0.f;
#pragma unroll
        for (int kt = 0; kt < 2; ++kt) {
#pragma unroll
            for (int g = 0; g < 4; ++g) {
                const float p0 = __builtin_amdgcn_exp2f(z[kt][g * 4 + 0]);
                const float p1 = __builtin_amdgcn_exp2f(z[kt][g * 4 + 1]);
                const float p2 = __builtin_amdgcn_exp2f(z[kt][g * 4 + 2]);
                const float p3 = __builtin_amdgcn_exp2f(z[kt][g * 4 + 3]);
                lp += (p0 + p1) + (p2 + p3);
                pkw[kt][g][0] = __builtin_bit_cast(unsigned int, __builtin_amdgcn_cvt_pkrtz(p0, p1));
                pkw[kt][g][1] = __builtin_bit_cast(unsigned int, __builtin_amdgcn_cvt_pkrtz(p2, p3));
            }
        }
        lpart += lp;

        // ---- exchange partner-destined groups: lane h sends groups {2sl+1-h} ----
        unsigned int rw[2][2][2];
#pragma unroll
        for (int kt = 0; kt < 2; ++kt)
#pragma unroll
            for (int sl = 0; sl < 2; ++sl)
#pragma unroll
                for (int hw = 0; hw < 2; ++hw) {
                    const unsigned int send = h ? pkw[kt][2 * sl][hw] : pkw[kt][2 * sl + 1][hw];
                    rw[kt][sl][hw] = (unsigned int)__shfl_xor((int)send, 32);
                }

        // ---- assemble P B-frags ----
        f16x8 pf[4];
#pragma unroll
        for (int s = 0; s < 4; ++s) {
            const int kt = s >> 1, sl = s & 1;
            u32x4 wd;
            wd[0] = h ? rw[kt][sl][0] : pkw[kt][2 * sl][0];
            wd[1] = h ? rw[kt][sl][1] : pkw[kt][2 * sl][1];
            wd[2] = h ? pkw[kt][2 * sl + 1][0] : rw[kt][sl][0];
            wd[3] = h ? pkw[kt][2 * sl + 1][1] : rw[kt][sl][1];
            pf[s] = __builtin_bit_cast(f16x8, wd);
        }

        // ---- O^T += V^T.P^T ----
#pragma unroll
        for (int s = 0; s < 4; ++s) {
            O[0] = __builtin_amdgcn_mfma_f32_32x32x16_f16(vv[s],     pf[s], O[0], 0, 0, 0);
            O[1] = __builtin_amdgcn_mfma_f32_32x32x16_f16(vv[4 + s], pf[s], O[1], 0, 0, 0);
        }
        // vv dead -> prefetch next chunk's V
        if (c + 1 < NCH) {
            const us* vn = vp + ((size_t)(c + 1) << 12);
#pragma unroll
            for (int u = 0; u < 8; ++u)
                vv[u] = LD8(vn + (((u >> 2) * 4 + (u & 3)) << 9));
        }
    }

    // ---- epilogue: l = own + partner half; normalize; b64 fp16 stores ----
    const float l  = lpart + __shfl_xor(lpart, 32);
    const float rl = 1.0f / l;
    const int sq = qt * 32 + m32;
    const size_t rowbase = (size_t)(b * SLEN + sq) * DMODEL + hd * HD;
#pragma unroll
    for (int dt = 0; dt < 2; ++dt) {
#pragma unroll
        for (int g = 0; g < 4; ++g) {
            us4 o4;
#pragma unroll
            for (int r2 = 0; r2 < 4; ++r2) o4[r2] = f16bits(O[dt][g * 4 + r2] * rl);
            *(us4*)&vals[rowbase + dt * 32 + 8 * g + 4 * h] = o4;
        }
    }
}

// ---------------- launch ----------------
extern "C" void kernel_launch(void* const* d_in, const int* in_sizes, int n_in,
                              void* d_out, int out_size, void* d_ws, size_t ws_size,
                              hipStream_t stream) {
    const float* x     = (const float*)d_in[0];
    const float* w_qkv = (const float*)d_in[1];
    const float* b_qkv = (const float*)d_in[2];
    const float* w_o   = (const float*)d_in[3];
    const float* b_o   = (const float*)d_in[4];
    float* out = (float*)d_out;

    const int M   = BATCH * SLEN;        // 4096
    const int XN  = M * DIN;             // 4,194,304
    const int WQN = E3 * DIN;            // 3,145,728
    const int WON = DMODEL * DMODEL;     // 1,048,576
    const size_t FN = (size_t)BATCH * NHEAD * HD * SLEN;   // 4,194,304 per tensor

    us* qfn = (us*)d_ws;                 // frag-native Q [FN]
    us* kfn = qfn + FN;                  // frag-native K [FN]
    us* vfn = kfn + FN;                  // frag-native V^T [FN]
    us* xh  = vfn + FN;                  // fp16 x [XN], reused for vals
    us* wq  = xh + XN;                   // fp16 w_qkv [WQN]
    us* wo  = wq + WQN;                  // fp16 w_o [WON]

    // 1) fp32 -> fp16 conversions, one launch
    cvt3_f16<<<dim3((XN + WQN + WON) / 2048), 256, 0, stream>>>(
        x, xh, XN, w_qkv, wq, WQN, w_o, wo);

    // 2) qkv projection -> frag-native Q (scaled), K, V buffers
    gemm_f16<true><<<dim3(E3 / 128, M / 128), 256, 0, stream>>>(
        xh, wq, b_qkv, nullptr, qfn, kfn, vfn, M, E3, DIN);

    // 3) attention -> vals fp16 (reuse x plane; x is dead)
    us* vals = xh;
    attn_mfma<<<dim3(SLEN / 128, BATCH * NHEAD), 256, 0, stream>>>(qfn, kfn, vfn, vals);

    // 4) out = vals @ w_o^T + b_o -> fp32
    gemm_f16<false><<<dim3(DMODEL / 128, M / 128), 256, 0, stream>>>(
        vals, wo, b_o, out, nullptr, nullptr, nullptr, M, DMODEL, DMODEL);
}